// Round 4
// baseline (29894.431 us; speedup 1.0000x reference)
//
#include <hip/hip_runtime.h>

// ---------------------------------------------------------------------------
// Net_SLSTM_TempAtten: 2-layer spiking LSTM, T=512, B=256, I=14, H=512, C=8.
// Persistent kernel, PLAIN launch (R4: hipLaunchCooperativeKernel silently
// failed -> out never written; groups are independent, so cooperative grid
// sync is unnecessary -- co-residency comes from 256 wgs x 1 wg/CU x 256 CUs,
// hand-rolled agent-scope group barriers in d_ws do the rest).
// 8 groups x 32 wgs x 256 thr; group g owns batch rows [32g,32g+32),
// wg cs owns h-cols [16cs,16cs+16).
// Split-fp16 (hi+lo) on ALL matmul operands -> ~fp32 accuracy:
//   A@B ~= Ah@Bh + Ah@Bl + Al@Bh   (lo*lo dropped, ~2^-22 relative)
// Weights hi (3 mats) + lo (Whh1,Whh2) register-resident; Wih2_lo in LDS.
// Activations exchanged hi+lo via fragment-linear fp16 ws buffers,
// double-buffered by parity; ONE agent-scope group barrier per step.
// R4: plain launch + merged gate-exchange LDS buffer (74 KB total LDS).
// ---------------------------------------------------------------------------

typedef _Float16 half8 __attribute__((ext_vector_type(8)));
typedef float    floatx4 __attribute__((ext_vector_type(4)));

#define T_STEPS 512
#define HDIM    512
#define KB      16          // 512/32 k-blocks
#define ROWS    32          // batch rows per group
#define HSLICE  16          // h columns per wg

#define ACT_ELEMS 16384     // 32 rows x 512 h (halves) = 32 KB
// buffer idx: 0=m1hi 1=m1lo 2=spk 3=m2hi 4=m2lo
#define WS_ACT_OFF 4096
#define WS_PART_OFF (WS_ACT_OFF + 2*5*8*ACT_ELEMS*2)   // 4096 + 2621440
#define WS_PART_BYTES (256*32*8*4)                     // 262144
#define WS_MEMSET_BYTES WS_PART_OFF

__device__ __forceinline__ float sigm(float v)  { return 1.0f/(1.0f + __expf(-v)); }
__device__ __forceinline__ float tanhf_(float v){ return 1.0f - 2.0f/(__expf(2.0f*v) + 1.0f); }

__device__ __forceinline__ void split16(float v, _Float16& h, _Float16& l) {
  h = (_Float16)v; l = (_Float16)(v - (float)h);
}

// fragment-linear index of activation element (b in [0,32), h in [0,512))
__device__ __forceinline__ int pidx(int b, int h) {
  return (((h >> 5)*2 + (b >> 4))*64 + (((h >> 3) & 3)*16 + (b & 15)))*8 + (h & 7);
}

#define MFMA(A,B,C) __builtin_amdgcn_mfma_f32_16x16x32_f16((A),(B),(C),0,0,0)

__global__ __launch_bounds__(256, 1)
void slstm_kernel(const float* __restrict__ x,
                  const float* __restrict__ Wih1, const float* __restrict__ Whh1,
                  const float* __restrict__ bih1, const float* __restrict__ bhh1,
                  const float* __restrict__ thr1p,
                  const float* __restrict__ Wih2, const float* __restrict__ Whh2,
                  const float* __restrict__ bih2, const float* __restrict__ bhh2,
                  const float* __restrict__ thr2p,
                  const float* __restrict__ Wfc,  const float* __restrict__ bfc,
                  float* __restrict__ out, unsigned char* __restrict__ ws)
{
  const int tid  = threadIdx.x;
  const int bid  = blockIdx.x;
  const int g    = bid & 7;    // group (XCD heuristic; correctness via agent fences)
  const int cs   = bid >> 3;   // column slice 0..31
  const int wave = tid >> 6;   // == gate index q (0=i,1=f,2=g,3=o)
  const int lane = tid & 63;
  const int l15  = lane & 15;
  const int lg   = lane >> 4;

  __shared__ float    gbuf[4*ROWS*HSLICE];   // 8 KB gate exchange (both phases)
  __shared__ _Float16 xstage[ROWS*32];       // 2 KB: k0-13 x_hi,14/15=1,16-29 x_lo
  __shared__ float    b2s[64];               // layer-2 combined bias slice (fp32)
  __shared__ _Float16 wIloLds[4*KB*64*8];    // 64 KB: Wih2_lo B-fragments

  unsigned* cntp = (unsigned*)(ws) + (size_t)g*16;   // 64B-spaced counters
  _Float16* actb = (_Float16*)(ws + WS_ACT_OFF);
  float*    partb = (float*)(ws + WS_PART_OFF);

  // ---- load register-resident weight B-fragments, split hi/lo (once) ----
  // B-frag (16x16x32 f16): lane holds B[k=(lane>>4)*8+j][col=lane&15]
  const int gc = wave*HDIM + cs*HSLICE + l15;   // global gate column
  const int kr = lg*8;
  half8 wAh[KB], wAl[KB], wIh[KB], wHh[KB], wHl[KB];
#pragma unroll
  for (int kb = 0; kb < KB; ++kb) {
    const float* p1 = Whh1 + (size_t)gc*HDIM + kb*32 + kr;
    const float* p2 = Wih2 + (size_t)gc*HDIM + kb*32 + kr;
    const float* p3 = Whh2 + (size_t)gc*HDIM + kb*32 + kr;
    half8 ah, al, ih, il, hh, hl;
#pragma unroll
    for (int j = 0; j < 8; ++j) {
      _Float16 sh, sl;
      split16(p1[j], sh, sl); ah[j] = sh; al[j] = sl;
      split16(p2[j], sh, sl); ih[j] = sh; il[j] = sl;
      split16(p3[j], sh, sl); hh[j] = sh; hl[j] = sl;
    }
    wAh[kb] = ah; wAl[kb] = al; wIh[kb] = ih; wHh[kb] = hh; wHl[kb] = hl;
    ((half8*)wIloLds)[(wave*KB + kb)*64 + lane] = il;  // lo of Wih2 -> LDS
  }
  // x-path B-frags (K=32): wX1 = [Wih1_hi(k<14), bias_hi@14, bias_lo@15, 0...]
  //                        wX2 = [Wih1_lo(k<14), 0, 0, Wih1_hi(k-16 for 16..29), 0, 0]
  half8 wX1, wX2;
#pragma unroll
  for (int j = 0; j < 8; ++j) {
    int k = kr + j;
    float v1 = 0.0f, v2 = 0.0f;
    _Float16 h, l;
    if (k < 14) {
      split16(Wih1[(size_t)gc*14 + k], h, l);
      v1 = (float)h; v2 = (float)l;
    } else if (k == 14) {
      split16(bih1[gc] + bhh1[gc], h, l);
      v1 = (float)h;
    } else if (k == 15) {
      split16(bih1[gc] + bhh1[gc], h, l);
      v1 = (float)l;
    } else if (k >= 16 && k <= 29) {
      split16(Wih1[(size_t)gc*14 + (k - 16)], h, l);
      v2 = (float)h;
    }
    wX1[j] = (_Float16)v1; wX2[j] = (_Float16)v2;
  }

  if (tid < 64) {
    int q = tid >> 4, h = tid & 15;
    int gcl = q*HDIM + cs*HSLICE + h;
    b2s[tid] = bih2[gcl] + bhh2[gcl];
  }
  for (int idx = tid; idx < ROWS*32; idx += 256) {  // constant lanes of xstage
    int k = idx & 31;
    if (k == 14 || k == 15)      xstage[idx] = (_Float16)1.0f;
    else if (k >= 30)            xstage[idx] = (_Float16)0.0f;
  }
  __syncthreads();   // wIloLds / b2s / xstage consts ready

  const float thr1 = thr1p[0], thr2 = thr2p[0];
  const int h_loc = tid & 15;
  const int b0    = tid >> 4;          // ew rows: b0 and b0+16
  const int hg    = cs*HSLICE + h_loc; // global h owned by this thread
  const int r0 = tid/14,        k0 = tid%14;
  const int i1 = tid + 256;
  const int r1 = i1/14,         k1 = i1%14;

  float syn1[2] = {0,0}, m1p[2] = {0,0}, syn2[2] = {0,0}, m2p[2] = {0,0};
  float accf[2] = {0,0};
  const float invn = (1.0f - __expf(-0.05f)) / (1.0f - __expf(-0.05f*512.0f));

  int bar_dead = 0;

  for (int t = 0; t < T_STEPS; ++t) {
    const int wp = t & 1, rp = wp ^ 1;

    // ---- stage x_t into LDS, split hi/lo ----
    // (this __syncthreads also separates prev-step ew2 gbuf reads from
    //  this step's phase-A gbuf writes)
    const float* xt = x + ((size_t)t*256 + (size_t)g*ROWS)*14;
    {
      _Float16 h, l; split16(xt[r0*14 + k0], h, l);
      xstage[r0*32 + k0] = h; xstage[r0*32 + 16 + k0] = l;
    }
    if (i1 < 448) {
      _Float16 h, l; split16(xt[r1*14 + k1], h, l);
      xstage[r1*32 + k1] = h; xstage[r1*32 + 16 + k1] = l;
    }
    __syncthreads();

    // ---- phase A: gates1 = x@Wih1^T + bias1 + mem1@Whh1^T (split) ----
    floatx4 acc0 = {0,0,0,0}, acc1 = {0,0,0,0};
    {
      half8 xa0 = *(const half8*)&xstage[l15*32 + kr];
      half8 xa1 = *(const half8*)&xstage[(16 + l15)*32 + kr];
      acc0 = MFMA(xa0, wX1, acc0);  acc1 = MFMA(xa1, wX1, acc1);
      acc0 = MFMA(xa0, wX2, acc0);  acc1 = MFMA(xa1, wX2, acc1);
    }
    const half8* AmH = (const half8*)(actb + (size_t)((rp*5 + 0)*8 + g)*ACT_ELEMS);
    const half8* AmL = (const half8*)(actb + (size_t)((rp*5 + 1)*8 + g)*ACT_ELEMS);
#pragma unroll
    for (int kb = 0; kb < KB; ++kb) {
      half8 a0h = AmH[(kb*2 + 0)*64 + lane];
      half8 a1h = AmH[(kb*2 + 1)*64 + lane];
      half8 a0l = AmL[(kb*2 + 0)*64 + lane];
      half8 a1l = AmL[(kb*2 + 1)*64 + lane];
      acc0 = MFMA(a0h, wAh[kb], acc0);  acc1 = MFMA(a1h, wAh[kb], acc1);
      acc0 = MFMA(a0h, wAl[kb], acc0);  acc1 = MFMA(a1h, wAl[kb], acc1);
      acc0 = MFMA(a0l, wAh[kb], acc0);  acc1 = MFMA(a1l, wAh[kb], acc1);
    }
#pragma unroll
    for (int p = 0; p < 4; ++p) {   // C-frag: row=(lane>>4)*4+p, col=lane&15
      gbuf[(wave*ROWS +      lg*4 + p)*HSLICE + l15] = acc0[p];
      gbuf[(wave*ROWS + 16 + lg*4 + p)*HSLICE + l15] = acc1[p];
    }
    __syncthreads();

    // ---- layer-1 elementwise ----
    _Float16* m1hW = actb + (size_t)((wp*5 + 0)*8 + g)*ACT_ELEMS;
    _Float16* m1lW = actb + (size_t)((wp*5 + 1)*8 + g)*ACT_ELEMS;
    _Float16* spW  = actb + (size_t)((wp*5 + 2)*8 + g)*ACT_ELEMS;
#pragma unroll
    for (int e = 0; e < 2; ++e) {
      int b = b0 + e*16;
      float pi = gbuf[(0*ROWS + b)*HSLICE + h_loc];
      float pf = gbuf[(1*ROWS + b)*HSLICE + h_loc];
      float pg = gbuf[(2*ROWS + b)*HSLICE + h_loc];
      float po = gbuf[(3*ROWS + b)*HSLICE + h_loc];
      float iv = sigm(pi), fv = sigm(pf), gv = tanhf_(pg), ov = sigm(po);
      float cnew = fv*syn1[e] + iv*gv;
      syn1[e] = cnew;
      float hnew = ov*tanhf_(cnew);
      float m1 = hnew - ((m1p[e] > thr1) ? thr1 : 0.0f);   // detached reset
      m1p[e] = m1;
      float spk = ((m1 - thr1) > 0.0f) ? 1.0f : 0.0f;      // exact in fp16
      int idx = pidx(b, hg);
      _Float16 mh, ml; split16(m1, mh, ml);
      m1hW[idx] = mh; m1lW[idx] = ml; spW[idx] = (_Float16)spk;
    }

    // ---- group barrier (one per step) ----
    __threadfence();
    __syncthreads();   // also separates ew1 gbuf reads from phase-B gbuf writes
    if (tid == 0 && !bar_dead) {
      __hip_atomic_fetch_add(cntp, 1u, __ATOMIC_RELEASE, __HIP_MEMORY_SCOPE_AGENT);
      unsigned target = 32u*(unsigned)(t + 1);
      int tries = 0;
      while (__hip_atomic_load(cntp, __ATOMIC_ACQUIRE, __HIP_MEMORY_SCOPE_AGENT) < target) {
        __builtin_amdgcn_s_sleep(1);
        if (++tries > (1 << 21)) { bar_dead = 1; break; }   // anti-hang fuse
      }
    }
    __syncthreads();
    __threadfence();

    // ---- phase B: gates2 = spk1@Wih2^T + mem2@Whh2^T + bias2 (split) ----
    floatx4 aS0 = {0,0,0,0}, aS1 = {0,0,0,0}, aM0 = {0,0,0,0}, aM1 = {0,0,0,0};
    const half8* Sp  = (const half8*)(actb + (size_t)((wp*5 + 2)*8 + g)*ACT_ELEMS);
    const half8* M2H = (const half8*)(actb + (size_t)((rp*5 + 3)*8 + g)*ACT_ELEMS);
    const half8* M2L = (const half8*)(actb + (size_t)((rp*5 + 4)*8 + g)*ACT_ELEMS);
#pragma unroll
    for (int kb = 0; kb < KB; ++kb) {
      half8 s0  = Sp[(kb*2 + 0)*64 + lane];
      half8 s1  = Sp[(kb*2 + 1)*64 + lane];
      half8 m0h = M2H[(kb*2 + 0)*64 + lane];
      half8 m1h = M2H[(kb*2 + 1)*64 + lane];
      half8 m0l = M2L[(kb*2 + 0)*64 + lane];
      half8 m1l = M2L[(kb*2 + 1)*64 + lane];
      half8 wIl = ((const half8*)wIloLds)[(wave*KB + kb)*64 + lane];
      aS0 = MFMA(s0,  wIh[kb], aS0);  aS1 = MFMA(s1,  wIh[kb], aS1);
      aS0 = MFMA(s0,  wIl,     aS0);  aS1 = MFMA(s1,  wIl,     aS1);
      aM0 = MFMA(m0h, wHh[kb], aM0);  aM1 = MFMA(m1h, wHh[kb], aM1);
      aM0 = MFMA(m0h, wHl[kb], aM0);  aM1 = MFMA(m1h, wHl[kb], aM1);
      aM0 = MFMA(m0l, wHh[kb], aM0);  aM1 = MFMA(m1l, wHh[kb], aM1);
    }
#pragma unroll
    for (int p = 0; p < 4; ++p) {
      gbuf[(wave*ROWS +      lg*4 + p)*HSLICE + l15] = aS0[p] + aM0[p];
      gbuf[(wave*ROWS + 16 + lg*4 + p)*HSLICE + l15] = aS1[p] + aM1[p];
    }
    __syncthreads();

    // ---- layer-2 elementwise + temporal-attention accumulation ----
    float wt = __expf(0.05f*(float)(t + 1 - T_STEPS)) * invn;  // exp(-.05*(511-t))/norm
    _Float16* m2hW = actb + (size_t)((wp*5 + 3)*8 + g)*ACT_ELEMS;
    _Float16* m2lW = actb + (size_t)((wp*5 + 4)*8 + g)*ACT_ELEMS;
#pragma unroll
    for (int e = 0; e < 2; ++e) {
      int b = b0 + e*16;
      float pi = gbuf[(0*ROWS + b)*HSLICE + h_loc] + b2s[0*16 + h_loc];
      float pf = gbuf[(1*ROWS + b)*HSLICE + h_loc] + b2s[1*16 + h_loc];
      float pg = gbuf[(2*ROWS + b)*HSLICE + h_loc] + b2s[2*16 + h_loc];
      float po = gbuf[(3*ROWS + b)*HSLICE + h_loc] + b2s[3*16 + h_loc];
      float iv = sigm(pi), fv = sigm(pf), gv = tanhf_(pg), ov = sigm(po);
      float cnew = fv*syn2[e] + iv*gv;
      syn2[e] = cnew;
      float hnew = ov*tanhf_(cnew);
      float m2 = hnew - ((m2p[e] > thr2) ? thr2 : 0.0f);
      m2p[e] = m2;
      accf[e] += wt * m2;
      int idx = pidx(b, hg);
      _Float16 mh, ml; split16(m2, mh, ml);
      m2hW[idx] = mh; m2lW[idx] = ml;
    }
    // no 2nd barrier: parity double-buffering + step-t barrier cover all hazards
  }

  // ---- epilogue: final_mem @ Wfc^T + bfc ----
  float wfc[8];
#pragma unroll
  for (int c = 0; c < 8; ++c) wfc[c] = Wfc[c*HDIM + hg];
  float part[2][8];
#pragma unroll
  for (int e = 0; e < 2; ++e)
#pragma unroll
    for (int c = 0; c < 8; ++c) part[e][c] = accf[e]*wfc[c];
#pragma unroll
  for (int off = 1; off < 16; off <<= 1) {   // reduce over the 16 h-lanes
#pragma unroll
    for (int e = 0; e < 2; ++e)
#pragma unroll
      for (int c = 0; c < 8; ++c)
        part[e][c] += __shfl_xor(part[e][c], off, 64);
  }
  if (h_loc == 0) {
#pragma unroll
    for (int e = 0; e < 2; ++e)
#pragma unroll
      for (int c = 0; c < 8; ++c)
        partb[((size_t)(g*32 + cs)*32 + (size_t)(b0 + e*16))*8 + c] = part[e][c];
  }

  __threadfence();
  __syncthreads();
  if (tid == 0 && !bar_dead) {
    __hip_atomic_fetch_add(cntp, 1u, __ATOMIC_RELEASE, __HIP_MEMORY_SCOPE_AGENT);
    unsigned target = 32u*513u;
    int tries = 0;
    while (__hip_atomic_load(cntp, __ATOMIC_ACQUIRE, __HIP_MEMORY_SCOPE_AGENT) < target) {
      __builtin_amdgcn_s_sleep(1);
      if (++tries > (1 << 21)) break;
    }
  }
  __syncthreads();
  __threadfence();

  if (cs == 0) {   // wg 0 of each group reduces its group's 32x8 outputs
    int b = tid >> 3, c = tid & 7;
    float s = bfc[c];
#pragma unroll 4
    for (int jj = 0; jj < 32; ++jj)
      s += partb[((size_t)(g*32 + jj)*32 + (size_t)b)*8 + c];
    out[(g*ROWS + b)*8 + c] = s;
  }
}

extern "C" void kernel_launch(void* const* d_in, const int* in_sizes, int n_in,
                              void* d_out, int out_size, void* d_ws, size_t ws_size,
                              hipStream_t stream) {
  (void)in_sizes; (void)n_in;
  const float* x    = (const float*)d_in[0];
  const float* Wih1 = (const float*)d_in[1];
  const float* Whh1 = (const float*)d_in[2];
  const float* bih1 = (const float*)d_in[3];
  const float* bhh1 = (const float*)d_in[4];
  const float* thr1 = (const float*)d_in[5];
  const float* Wih2 = (const float*)d_in[6];
  const float* Whh2 = (const float*)d_in[7];
  const float* bih2 = (const float*)d_in[8];
  const float* bhh2 = (const float*)d_in[9];
  const float* thr2 = (const float*)d_in[10];
  const float* Wfc  = (const float*)d_in[11];
  const float* bfc  = (const float*)d_in[12];
  float* out = (float*)d_out;
  unsigned char* ws = (unsigned char*)d_ws;

  if (ws_size < (size_t)(WS_PART_OFF + WS_PART_BYTES)) {
    // distinctive failure marker (huge values) instead of OOB writes
    hipError_t e1 = hipMemsetAsync(d_out, 0x7f, (size_t)out_size*4, stream);
    (void)e1;
    return;
  }
  // zero barrier counters + both activation parities (t=0 reads zeros = init state)
  hipError_t e2 = hipMemsetAsync(d_ws, 0, WS_MEMSET_BYTES, stream);
  (void)e2;

  // R4: PLAIN launch. 256 wgs x 1 wg/CU (74 KB LDS) on 256 CUs -> all
  // co-resident; groups are independent; barriers are hand-rolled in ws.
  slstm_kernel<<<dim3(256), dim3(256), 0, stream>>>(
      x, Wih1, Whh1, bih1, bhh1, thr1,
      Wih2, Whh2, bih2, bhh2, thr2, Wfc, bfc, out, ws);
}

// Round 5
// 11001.266 us; speedup vs baseline: 2.7174x; 2.7174x over previous
//
#include <hip/hip_runtime.h>

// ---------------------------------------------------------------------------
// Net_SLSTM_TempAtten: 2-layer spiking LSTM, T=512, B=256, I=14, H=512, C=8.
// Persistent plain-launch kernel: 8 groups x 32 wgs x 256 thr; group g owns
// batch rows [32g,32g+32), wg cs owns h-cols [16cs,16cs+16).
// Split-fp16 (hi+lo) on all matmul operands -> ~fp32 accuracy.
// R5: FENCE-FREE exchange. R4 spent ~95% of step time in __threadfence()
// (agent fence = buffer_wbl2+buffer_inv full-L2 drain; WRITE_SIZE 660 MB
// = all activations through EA each step). Now all cross-wg data moves via
// RELAXED AGENT-SCOPE atomics (sc0 sc1 -> L3 coherence point, no L2 flush).
// Ordering: __syncthreads() drains vmcnt(0) before tid0's counter add
// (write-through stores acked at L3); consumers poll relaxed, then issue
// data loads in program order. No fences anywhere in the loop.
// ---------------------------------------------------------------------------

typedef _Float16 half8 __attribute__((ext_vector_type(8)));
typedef float    floatx4 __attribute__((ext_vector_type(4)));
typedef unsigned long long u64;

#define T_STEPS 512
#define HDIM    512
#define KB      16          // 512/32 k-blocks
#define ROWS    32          // batch rows per group
#define HSLICE  16          // h columns per wg

#define ACT_ELEMS 16384     // 32 rows x 512 h (halves) = 32 KB per buffer
// buffer idx: 0=m1hi 1=m1lo 2=spk 3=m2hi 4=m2lo ; x2 parity
#define WS_ACT_OFF 4096
#define WS_PART_OFF (WS_ACT_OFF + 2*5*8*ACT_ELEMS*2)   // 4096 + 2621440
#define WS_PART_BYTES (256*32*8*4)                     // 262144
#define WS_MEMSET_BYTES WS_PART_OFF

__device__ __forceinline__ float sigm(float v)  { return 1.0f/(1.0f + __expf(-v)); }
__device__ __forceinline__ float tanhf_(float v){ return 1.0f - 2.0f/(__expf(2.0f*v) + 1.0f); }

__device__ __forceinline__ void split16(float v, _Float16& h, _Float16& l) {
  h = (_Float16)v; l = (_Float16)(v - (float)h);
}
__device__ __forceinline__ unsigned pack2(_Float16 a, _Float16 b) {
  unsigned short ua = __builtin_bit_cast(unsigned short, a);
  unsigned short ub = __builtin_bit_cast(unsigned short, b);
  return (unsigned)ua | ((unsigned)ub << 16);
}

union H8Q { u64 q[2]; half8 v; };

// relaxed agent-scope accessors: plain global ops with sc0 sc1, no fences
__device__ __forceinline__ half8 ld_frag(const u64* p) {
  H8Q t;
  t.q[0] = __hip_atomic_load(p,     __ATOMIC_RELAXED, __HIP_MEMORY_SCOPE_AGENT);
  t.q[1] = __hip_atomic_load(p + 1, __ATOMIC_RELAXED, __HIP_MEMORY_SCOPE_AGENT);
  return t.v;
}
__device__ __forceinline__ void st_u32(unsigned* p, unsigned v) {
  __hip_atomic_store(p, v, __ATOMIC_RELAXED, __HIP_MEMORY_SCOPE_AGENT);
}

#define MFMA(A,B,C) __builtin_amdgcn_mfma_f32_16x16x32_f16((A),(B),(C),0,0,0)

__global__ __launch_bounds__(256, 1)
void slstm_kernel(const float* __restrict__ x,
                  const float* __restrict__ Wih1, const float* __restrict__ Whh1,
                  const float* __restrict__ bih1, const float* __restrict__ bhh1,
                  const float* __restrict__ thr1p,
                  const float* __restrict__ Wih2, const float* __restrict__ Whh2,
                  const float* __restrict__ bih2, const float* __restrict__ bhh2,
                  const float* __restrict__ thr2p,
                  const float* __restrict__ Wfc,  const float* __restrict__ bfc,
                  float* __restrict__ out, unsigned char* __restrict__ ws)
{
  const int tid  = threadIdx.x;
  const int bid  = blockIdx.x;
  const int g    = bid & 7;    // group (XCD heuristic; correctness via L3 atomics)
  const int cs   = bid >> 3;   // column slice 0..31
  const int wave = tid >> 6;   // == gate index q (0=i,1=f,2=g,3=o)
  const int lane = tid & 63;
  const int l15  = lane & 15;
  const int lg   = lane >> 4;

  __shared__ float    gbuf[4*ROWS*HSLICE];   // 8 KB gate exchange (both phases)
  __shared__ _Float16 xstage[ROWS*32];       // 2 KB: k0-13 x_hi,14/15=1,16-29 x_lo
  __shared__ float    b2s[64];               // layer-2 combined bias slice (fp32)
  __shared__ _Float16 wIloLds[4*KB*64*8];    // 64 KB: Wih2_lo B-fragments

  unsigned* cntp = (unsigned*)(ws) + (size_t)g*16;   // 64B-spaced counters
  _Float16* actb = (_Float16*)(ws + WS_ACT_OFF);
  float*    partb = (float*)(ws + WS_PART_OFF);

  // ---- load register-resident weight B-fragments, split hi/lo (once) ----
  // B-frag (16x16x32 f16): lane holds B[k=(lane>>4)*8+j][col=lane&15]
  const int gc = wave*HDIM + cs*HSLICE + l15;   // global gate column
  const int kr = lg*8;
  half8 wAh[KB], wAl[KB], wIh[KB], wHh[KB], wHl[KB];
#pragma unroll
  for (int kb = 0; kb < KB; ++kb) {
    const float* p1 = Whh1 + (size_t)gc*HDIM + kb*32 + kr;
    const float* p2 = Wih2 + (size_t)gc*HDIM + kb*32 + kr;
    const float* p3 = Whh2 + (size_t)gc*HDIM + kb*32 + kr;
    half8 ah, al, ih, il, hh, hl;
#pragma unroll
    for (int j = 0; j < 8; ++j) {
      _Float16 sh, sl;
      split16(p1[j], sh, sl); ah[j] = sh; al[j] = sl;
      split16(p2[j], sh, sl); ih[j] = sh; il[j] = sl;
      split16(p3[j], sh, sl); hh[j] = sh; hl[j] = sl;
    }
    wAh[kb] = ah; wAl[kb] = al; wIh[kb] = ih; wHh[kb] = hh; wHl[kb] = hl;
    ((half8*)wIloLds)[(wave*KB + kb)*64 + lane] = il;  // lo of Wih2 -> LDS
  }
  // x-path B-frags (K=32): wX1 = [Wih1_hi(k<14), bias_hi@14, bias_lo@15, 0...]
  //                        wX2 = [Wih1_lo(k<14), 0, 0, Wih1_hi(k-16, 16..29), 0, 0]
  half8 wX1, wX2;
#pragma unroll
  for (int j = 0; j < 8; ++j) {
    int k = kr + j;
    float v1 = 0.0f, v2 = 0.0f;
    _Float16 h, l;
    if (k < 14) {
      split16(Wih1[(size_t)gc*14 + k], h, l);
      v1 = (float)h; v2 = (float)l;
    } else if (k == 14) {
      split16(bih1[gc] + bhh1[gc], h, l);
      v1 = (float)h;
    } else if (k == 15) {
      split16(bih1[gc] + bhh1[gc], h, l);
      v1 = (float)l;
    } else if (k >= 16 && k <= 29) {
      split16(Wih1[(size_t)gc*14 + (k - 16)], h, l);
      v2 = (float)h;
    }
    wX1[j] = (_Float16)v1; wX2[j] = (_Float16)v2;
  }

  if (tid < 64) {
    int q = tid >> 4, h = tid & 15;
    int gcl = q*HDIM + cs*HSLICE + h;
    b2s[tid] = bih2[gcl] + bhh2[gcl];
  }
  for (int idx = tid; idx < ROWS*32; idx += 256) {  // constant lanes of xstage
    int k = idx & 31;
    if (k == 14 || k == 15)      xstage[idx] = (_Float16)1.0f;
    else if (k >= 30)            xstage[idx] = (_Float16)0.0f;
  }
  __syncthreads();   // wIloLds / b2s / xstage consts ready

  const float thr1 = thr1p[0], thr2 = thr2p[0];
  // elementwise ownership: thread = (row eb, h-pair ehl) -> one u32 per buffer
  const int eb  = tid >> 3;            // row 0..31
  const int ehl = (tid & 7)*2;         // local h pair base 0,2,..14
  const int ehg = cs*HSLICE + ehl;     // global h (even)
  // fragment-granule (16B) index of (eb, ehg):
  const int g16 = ((ehg >> 5)*2 + (eb >> 4))*64 + ((ehg >> 3) & 3)*16 + (eb & 15);
  const int u32i = g16*4 + ((ehg & 7) >> 1);   // u32 index within a buffer
  const int r0 = tid/14,  k0 = tid%14;
  const int i1 = tid + 256;
  const int r1 = i1/14,   k1 = i1%14;

  float syn1[2] = {0,0}, m1p[2] = {0,0}, syn2[2] = {0,0}, m2p[2] = {0,0};
  float accf[2] = {0,0};
  const float invn = (1.0f - __expf(-0.05f)) / (1.0f - __expf(-0.05f*512.0f));

  int bar_dead = 0;

  for (int t = 0; t < T_STEPS; ++t) {
    const int wp = t & 1, rp = wp ^ 1;

    // ---- stage x_t into LDS, split hi/lo (cached loads; x is read-only) ----
    const float* xt = x + ((size_t)t*256 + (size_t)g*ROWS)*14;
    {
      _Float16 h, l; split16(xt[r0*14 + k0], h, l);
      xstage[r0*32 + k0] = h; xstage[r0*32 + 16 + k0] = l;
    }
    if (i1 < 448) {
      _Float16 h, l; split16(xt[r1*14 + k1], h, l);
      xstage[r1*32 + k1] = h; xstage[r1*32 + 16 + k1] = l;
    }
    __syncthreads();

    // ---- phase A: gates1 = x@Wih1^T + bias1 + mem1@Whh1^T (split) ----
    floatx4 acc0 = {0,0,0,0}, acc1 = {0,0,0,0};
    {
      half8 xa0 = *(const half8*)&xstage[l15*32 + kr];
      half8 xa1 = *(const half8*)&xstage[(16 + l15)*32 + kr];
      acc0 = MFMA(xa0, wX1, acc0);  acc1 = MFMA(xa1, wX1, acc1);
      acc0 = MFMA(xa0, wX2, acc0);  acc1 = MFMA(xa1, wX2, acc1);
    }
    const u64* AmH = (const u64*)(actb + (size_t)((rp*5 + 0)*8 + g)*ACT_ELEMS);
    const u64* AmL = (const u64*)(actb + (size_t)((rp*5 + 1)*8 + g)*ACT_ELEMS);
#pragma unroll
    for (int kb = 0; kb < KB; ++kb) {
      half8 a0h = ld_frag(AmH + ((kb*2 + 0)*64 + lane)*2);
      half8 a1h = ld_frag(AmH + ((kb*2 + 1)*64 + lane)*2);
      half8 a0l = ld_frag(AmL + ((kb*2 + 0)*64 + lane)*2);
      half8 a1l = ld_frag(AmL + ((kb*2 + 1)*64 + lane)*2);
      acc0 = MFMA(a0h, wAh[kb], acc0);  acc1 = MFMA(a1h, wAh[kb], acc1);
      acc0 = MFMA(a0h, wAl[kb], acc0);  acc1 = MFMA(a1h, wAl[kb], acc1);
      acc0 = MFMA(a0l, wAh[kb], acc0);  acc1 = MFMA(a1l, wAh[kb], acc1);
    }
#pragma unroll
    for (int p = 0; p < 4; ++p) {   // C-frag: row=(lane>>4)*4+p, col=lane&15
      gbuf[(wave*ROWS +      lg*4 + p)*HSLICE + l15] = acc0[p];
      gbuf[(wave*ROWS + 16 + lg*4 + p)*HSLICE + l15] = acc1[p];
    }
    __syncthreads();

    // ---- layer-1 elementwise (row eb, columns ehg, ehg+1) ----
    {
      unsigned* m1hW = (unsigned*)(actb + (size_t)((wp*5 + 0)*8 + g)*ACT_ELEMS);
      unsigned* m1lW = (unsigned*)(actb + (size_t)((wp*5 + 1)*8 + g)*ACT_ELEMS);
      unsigned* spW  = (unsigned*)(actb + (size_t)((wp*5 + 2)*8 + g)*ACT_ELEMS);
      _Float16 mh[2], ml[2], sp[2];
#pragma unroll
      for (int c = 0; c < 2; ++c) {
        float pi = gbuf[(0*ROWS + eb)*HSLICE + ehl + c];
        float pf = gbuf[(1*ROWS + eb)*HSLICE + ehl + c];
        float pg = gbuf[(2*ROWS + eb)*HSLICE + ehl + c];
        float po = gbuf[(3*ROWS + eb)*HSLICE + ehl + c];
        float iv = sigm(pi), fv = sigm(pf), gv = tanhf_(pg), ov = sigm(po);
        float cnew = fv*syn1[c] + iv*gv;
        syn1[c] = cnew;
        float hnew = ov*tanhf_(cnew);
        float m1 = hnew - ((m1p[c] > thr1) ? thr1 : 0.0f);   // detached reset
        m1p[c] = m1;
        split16(m1, mh[c], ml[c]);
        sp[c] = ((m1 - thr1) > 0.0f) ? (_Float16)1.0f : (_Float16)0.0f;
      }
      st_u32(m1hW + u32i, pack2(mh[0], mh[1]));
      st_u32(m1lW + u32i, pack2(ml[0], ml[1]));
      st_u32(spW  + u32i, pack2(sp[0], sp[1]));
    }

    // ---- group barrier (one per step); syncthreads drains vmcnt(0) ----
    __syncthreads();
    if (tid == 0 && !bar_dead) {
      __hip_atomic_fetch_add(cntp, 1u, __ATOMIC_RELAXED, __HIP_MEMORY_SCOPE_AGENT);
      unsigned target = 32u*(unsigned)(t + 1);
      int tries = 0;
      while (__hip_atomic_load(cntp, __ATOMIC_RELAXED, __HIP_MEMORY_SCOPE_AGENT) < target) {
        __builtin_amdgcn_s_sleep(1);
        if (++tries > (1 << 21)) { bar_dead = 1; break; }   // anti-hang fuse
      }
    }
    __syncthreads();
    __atomic_signal_fence(__ATOMIC_SEQ_CST);   // compiler-only: no load hoisting

    // ---- phase B: gates2 = spk1@Wih2^T + mem2@Whh2^T + bias2 (split) ----
    floatx4 aS0 = {0,0,0,0}, aS1 = {0,0,0,0}, aM0 = {0,0,0,0}, aM1 = {0,0,0,0};
    const u64* Sp  = (const u64*)(actb + (size_t)((wp*5 + 2)*8 + g)*ACT_ELEMS);
    const u64* M2H = (const u64*)(actb + (size_t)((rp*5 + 3)*8 + g)*ACT_ELEMS);
    const u64* M2L = (const u64*)(actb + (size_t)((rp*5 + 4)*8 + g)*ACT_ELEMS);
#pragma unroll
    for (int kb = 0; kb < KB; ++kb) {
      half8 s0  = ld_frag(Sp  + ((kb*2 + 0)*64 + lane)*2);
      half8 s1  = ld_frag(Sp  + ((kb*2 + 1)*64 + lane)*2);
      half8 m0h = ld_frag(M2H + ((kb*2 + 0)*64 + lane)*2);
      half8 m1h = ld_frag(M2H + ((kb*2 + 1)*64 + lane)*2);
      half8 m0l = ld_frag(M2L + ((kb*2 + 0)*64 + lane)*2);
      half8 m1l = ld_frag(M2L + ((kb*2 + 1)*64 + lane)*2);
      half8 wIl = ((const half8*)wIloLds)[(wave*KB + kb)*64 + lane];
      aS0 = MFMA(s0,  wIh[kb], aS0);  aS1 = MFMA(s1,  wIh[kb], aS1);
      aS0 = MFMA(s0,  wIl,     aS0);  aS1 = MFMA(s1,  wIl,     aS1);
      aM0 = MFMA(m0h, wHh[kb], aM0);  aM1 = MFMA(m1h, wHh[kb], aM1);
      aM0 = MFMA(m0h, wHl[kb], aM0);  aM1 = MFMA(m1h, wHl[kb], aM1);
      aM0 = MFMA(m0l, wHh[kb], aM0);  aM1 = MFMA(m1l, wHh[kb], aM1);
    }
#pragma unroll
    for (int p = 0; p < 4; ++p) {
      gbuf[(wave*ROWS +      lg*4 + p)*HSLICE + l15] = aS0[p] + aM0[p];
      gbuf[(wave*ROWS + 16 + lg*4 + p)*HSLICE + l15] = aS1[p] + aM1[p];
    }
    __syncthreads();

    // ---- layer-2 elementwise + temporal-attention accumulation ----
    float wt = __expf(0.05f*(float)(t + 1 - T_STEPS)) * invn;  // exp(-.05*(511-t))/norm
    {
      unsigned* m2hW = (unsigned*)(actb + (size_t)((wp*5 + 3)*8 + g)*ACT_ELEMS);
      unsigned* m2lW = (unsigned*)(actb + (size_t)((wp*5 + 4)*8 + g)*ACT_ELEMS);
      _Float16 mh[2], ml[2];
#pragma unroll
      for (int c = 0; c < 2; ++c) {
        float pi = gbuf[(0*ROWS + eb)*HSLICE + ehl + c] + b2s[0*16 + ehl + c];
        float pf = gbuf[(1*ROWS + eb)*HSLICE + ehl + c] + b2s[1*16 + ehl + c];
        float pg = gbuf[(2*ROWS + eb)*HSLICE + ehl + c] + b2s[2*16 + ehl + c];
        float po = gbuf[(3*ROWS + eb)*HSLICE + ehl + c] + b2s[3*16 + ehl + c];
        float iv = sigm(pi), fv = sigm(pf), gv = tanhf_(pg), ov = sigm(po);
        float cnew = fv*syn2[c] + iv*gv;
        syn2[c] = cnew;
        float hnew = ov*tanhf_(cnew);
        float m2 = hnew - ((m2p[c] > thr2) ? thr2 : 0.0f);
        m2p[c] = m2;
        accf[c] += wt * m2;
        split16(m2, mh[c], ml[c]);
      }
      st_u32(m2hW + u32i, pack2(mh[0], mh[1]));
      st_u32(m2lW + u32i, pack2(ml[0], ml[1]));
    }
    // no 2nd barrier: parity double-buffering + step-t barrier cover all hazards
  }

  // ---- epilogue: final_mem @ Wfc^T + bfc ----
  // thread owns (row eb, cols ehg, ehg+1); reduce over the 8 h-pair lanes
  float wfc0[8], wfc1[8];
#pragma unroll
  for (int c = 0; c < 8; ++c) {
    wfc0[c] = Wfc[c*HDIM + ehg];
    wfc1[c] = Wfc[c*HDIM + ehg + 1];
  }
  float part[8];
#pragma unroll
  for (int c = 0; c < 8; ++c) part[c] = accf[0]*wfc0[c] + accf[1]*wfc1[c];
#pragma unroll
  for (int off = 1; off < 8; off <<= 1) {   // reduce over 8 h-pair lanes
#pragma unroll
    for (int c = 0; c < 8; ++c)
      part[c] += __shfl_xor(part[c], off, 64);
  }
  {  // every lane stores one class c = lane&7 for its row eb
    int c = tid & 7;
    float v = part[c];
    __hip_atomic_store(&partb[((size_t)(g*32 + cs)*32 + (size_t)eb)*8 + c], v,
                       __ATOMIC_RELAXED, __HIP_MEMORY_SCOPE_AGENT);
  }

  __syncthreads();   // drain partb stores (vmcnt 0 before barrier)
  if (tid == 0 && !bar_dead) {
    __hip_atomic_fetch_add(cntp, 1u, __ATOMIC_RELAXED, __HIP_MEMORY_SCOPE_AGENT);
    unsigned target = 32u*513u;
    int tries = 0;
    while (__hip_atomic_load(cntp, __ATOMIC_RELAXED, __HIP_MEMORY_SCOPE_AGENT) < target) {
      __builtin_amdgcn_s_sleep(1);
      if (++tries > (1 << 21)) break;
    }
  }
  __syncthreads();
  __atomic_signal_fence(__ATOMIC_SEQ_CST);

  if (cs == 0) {   // wg 0 of each group reduces its group's 32x8 outputs
    int b = tid >> 3, c = tid & 7;
    float s = bfc[c];
#pragma unroll 4
    for (int jj = 0; jj < 32; ++jj)
      s += __hip_atomic_load(&partb[((size_t)(g*32 + jj)*32 + (size_t)b)*8 + c],
                             __ATOMIC_RELAXED, __HIP_MEMORY_SCOPE_AGENT);
    out[(g*ROWS + b)*8 + c] = s;
  }
}

extern "C" void kernel_launch(void* const* d_in, const int* in_sizes, int n_in,
                              void* d_out, int out_size, void* d_ws, size_t ws_size,
                              hipStream_t stream) {
  (void)in_sizes; (void)n_in;
  const float* x    = (const float*)d_in[0];
  const float* Wih1 = (const float*)d_in[1];
  const float* Whh1 = (const float*)d_in[2];
  const float* bih1 = (const float*)d_in[3];
  const float* bhh1 = (const float*)d_in[4];
  const float* thr1 = (const float*)d_in[5];
  const float* Wih2 = (const float*)d_in[6];
  const float* Whh2 = (const float*)d_in[7];
  const float* bih2 = (const float*)d_in[8];
  const float* bhh2 = (const float*)d_in[9];
  const float* thr2 = (const float*)d_in[10];
  const float* Wfc  = (const float*)d_in[11];
  const float* bfc  = (const float*)d_in[12];
  float* out = (float*)d_out;
  unsigned char* ws = (unsigned char*)d_ws;

  if (ws_size < (size_t)(WS_PART_OFF + WS_PART_BYTES)) {
    hipError_t e1 = hipMemsetAsync(d_out, 0x7f, (size_t)out_size*4, stream);
    (void)e1;
    return;
  }
  // zero barrier counters + both activation parities (t=0 reads zeros = init state)
  hipError_t e2 = hipMemsetAsync(d_ws, 0, WS_MEMSET_BYTES, stream);
  (void)e2;

  slstm_kernel<<<dim3(256), dim3(256), 0, stream>>>(
      x, Wih1, Whh1, bih1, bhh1, thr1,
      Wih2, Whh2, bih2, bhh2, thr2, Wfc, bfc, out, ws);
}

// Round 7
// 4821.280 us; speedup vs baseline: 6.2005x; 2.2818x over previous
//
#include <hip/hip_runtime.h>

// ---------------------------------------------------------------------------
// Net_SLSTM_TempAtten: 2-layer spiking LSTM, T=512, B=256, I=14, H=512, C=8.
// R7 = R5's PROVEN-CORRECT exchange semantics (blockIdx groups, MALL-coherent
// sc0sc1 loads/stores, agent-scope barrier) + R6's k-split efficiency + the
// register-residency fix:
//  - amdgpu_waves_per_eu(1,1): R5/R6 compiled at 236 VGPRs (allocator
//    occupancy heuristic) and spilled the 320-VGPR weight set to scratch ->
//    FETCH_SIZE 381 MB of scratch reloads inside the MFMA loop. Forcing
//    min=max=1 wave/EU unlocks the full 512-VGPR budget.
//  - k-split: wave w owns kb in [4w,4w+4) for ALL 4 gates -> 4x fewer
//    exchange loads; gate partials summed via padded LDS pbuf.
//  - batched 16B sc0sc1 loads with pipelined s_waitcnt vmcnt(8)->(0).
// R6's XCD-local L2 scheme is shelved: it silently requires an exactly-even
// wg->XCD distribution (absmax 2.7e-2 = one aliased + one missing slot).
// Split-fp16 (hi+lo) numerics unchanged (R4/R5: absmax 0.0).
// ---------------------------------------------------------------------------

typedef _Float16 half8 __attribute__((ext_vector_type(8)));
typedef float    floatx4 __attribute__((ext_vector_type(4)));
typedef int      int4v  __attribute__((ext_vector_type(4)));

union H8 { int4v i; half8 h; };

#define T_STEPS 512
#define HDIM    512
#define ROWS    32
#define HSLICE  16
#define ACT_ELEMS 16384     // 32 rows x 512 h halves = 32 KB per buffer
// buffers: 0=m1hi 1=m1lo 2=spk 3=m2hi 4=m2lo ; x2 parity
#define WS_ACT_OFF 4096
#define WS_PART_OFF (WS_ACT_OFF + 2*5*8*ACT_ELEMS*2)   // 4096 + 2621440
#define WS_PART_BYTES (256*32*8*4)                     // 262144
#define WS_MEMSET_BYTES WS_PART_OFF
#define PB_STRIDE 17        // pbuf row pad: breaks power-of-2 bank aliasing

__device__ __forceinline__ float sigm(float v)  { return 1.0f/(1.0f + __expf(-v)); }
__device__ __forceinline__ float tanhf_(float v){ return 1.0f - 2.0f/(__expf(2.0f*v) + 1.0f); }
__device__ __forceinline__ void split16(float v, _Float16& h, _Float16& l) {
  h = (_Float16)v; l = (_Float16)(v - (float)h);
}
__device__ __forceinline__ unsigned pack2(_Float16 a, _Float16 b) {
  unsigned short ua = __builtin_bit_cast(unsigned short, a);
  unsigned short ub = __builtin_bit_cast(unsigned short, b);
  return (unsigned)ua | ((unsigned)ub << 16);
}

// 16B MALL-coherent load (bypass L1+L2, read the die-level coherence point).
// Value NOT ready until a subsequent s_waitcnt asm that ties the register.
#define LDG16(dst, ptr) \
  asm volatile("global_load_dwordx4 %0, %1, off sc0 sc1" : "=v"((dst).i) : "v"(ptr) : "memory")

// MALL-coherent u32 store (write-through; same codegen class R5 proved).
__device__ __forceinline__ void st_u32(unsigned* p, unsigned v) {
  __hip_atomic_store(p, v, __ATOMIC_RELAXED, __HIP_MEMORY_SCOPE_AGENT);
}

#define MFMA(A,B,C) __builtin_amdgcn_mfma_f32_16x16x32_f16((A),(B),(C),0,0,0)

__global__ __launch_bounds__(256) __attribute__((amdgpu_waves_per_eu(1, 1)))
void slstm_kernel(const float* __restrict__ x,
                  const float* __restrict__ Wih1, const float* __restrict__ Whh1,
                  const float* __restrict__ bih1, const float* __restrict__ bhh1,
                  const float* __restrict__ thr1p,
                  const float* __restrict__ Wih2, const float* __restrict__ Whh2,
                  const float* __restrict__ bih2, const float* __restrict__ bhh2,
                  const float* __restrict__ thr2p,
                  const float* __restrict__ Wfc,  const float* __restrict__ bfc,
                  float* __restrict__ out, unsigned char* __restrict__ ws)
{
  const int tid  = threadIdx.x;
  const int bid  = blockIdx.x;
  const int g    = bid & 7;    // logical group: deterministic full slot coverage
  const int cs   = bid >> 3;   // column slice 0..31
  const int wave = tid >> 6;
  const int lane = tid & 63;
  const int l15  = lane & 15;
  const int lg   = lane >> 4;
  const int kr   = lg*8;

  __shared__ _Float16 wIloLds[4*16*64*8];          // 64 KB: Wih2_lo B-frags
  __shared__ float    pbuf[4][128*PB_STRIDE + 16]; // ~34 KB: per-wave partials
  __shared__ _Float16 xstage[ROWS*32];             // 2 KB
  __shared__ float    b2s[64];

  unsigned* cntp  = (unsigned*)ws + (size_t)g*16;  // 64B-spaced barrier counters
  _Float16* actb  = (_Float16*)(ws + WS_ACT_OFF);
  float*    partb = (float*)(ws + WS_PART_OFF);

  // ---- weight B-fragments, split hi/lo; K-split: wave w owns kb=4w..4w+3 ----
  // B-frag (16x16x32 f16): lane holds B[k=(lane>>4)*8+j][col=lane&15]
  half8 wAh[4][4], wAl[4][4], wIh[4][4], wHh[4][4], wHl[4][4];
#pragma unroll
  for (int q = 0; q < 4; ++q) {
    const int gcq = q*HDIM + cs*HSLICE + l15;
#pragma unroll
    for (int kl = 0; kl < 4; ++kl) {
      const int kb = wave*4 + kl;
      const float* p1 = Whh1 + (size_t)gcq*HDIM + kb*32 + kr;
      const float* p2 = Wih2 + (size_t)gcq*HDIM + kb*32 + kr;
      const float* p3 = Whh2 + (size_t)gcq*HDIM + kb*32 + kr;
      half8 ah, al, ih, il, hh, hl;
#pragma unroll
      for (int j = 0; j < 8; ++j) {
        _Float16 sh, sl;
        split16(p1[j], sh, sl); ah[j] = sh; al[j] = sl;
        split16(p2[j], sh, sl); ih[j] = sh; il[j] = sl;
        split16(p3[j], sh, sl); hh[j] = sh; hl[j] = sl;
      }
      wAh[q][kl] = ah; wAl[q][kl] = al; wIh[q][kl] = ih;
      wHh[q][kl] = hh; wHl[q][kl] = hl;
      *(half8*)&wIloLds[(((wave*4 + kl)*4 + q)*64 + lane)*8] = il;
    }
  }
  // x-path (gate = wave): K=32 padded; wX1=[Wih1_hi, bias_hi@14, bias_lo@15],
  // wX2=[Wih1_lo(k<14), Wih1_hi(k-16 for 16..29)]
  half8 wX1, wX2;
  {
    const int gcx = wave*HDIM + cs*HSLICE + l15;
#pragma unroll
    for (int j = 0; j < 8; ++j) {
      int k = kr + j;
      float v1 = 0.0f, v2 = 0.0f;
      _Float16 h, l;
      if (k < 14)       { split16(Wih1[(size_t)gcx*14 + k], h, l); v1 = (float)h; v2 = (float)l; }
      else if (k == 14) { split16(bih1[gcx] + bhh1[gcx], h, l); v1 = (float)h; }
      else if (k == 15) { split16(bih1[gcx] + bhh1[gcx], h, l); v1 = (float)l; }
      else if (k <= 29) { split16(Wih1[(size_t)gcx*14 + (k - 16)], h, l); v2 = (float)h; }
      wX1[j] = (_Float16)v1; wX2[j] = (_Float16)v2;
    }
  }
  if (tid < 64) {
    int q = tid >> 4, h = tid & 15;
    int gcl = q*HDIM + cs*HSLICE + h;
    b2s[tid] = bih2[gcl] + bhh2[gcl];
  }
  for (int idx = tid; idx < ROWS*32; idx += 256) {
    int k = idx & 31;
    if (k == 14 || k == 15) xstage[idx] = (_Float16)1.0f;
    else if (k >= 30)       xstage[idx] = (_Float16)0.0f;
  }
  __syncthreads();

  const float thr1 = thr1p[0], thr2 = thr2p[0];
  const int eb  = tid >> 3;            // ew row 0..31
  const int ehl = (tid & 7)*2;         // ew local h pair
  const int ehg = cs*HSLICE + ehl;
  const int g16 = ((ehg >> 5)*2 + (eb >> 4))*64 + ((ehg >> 3) & 3)*16 + (eb & 15);
  const int u32i = g16*4 + ((ehg & 7) >> 1);
  const int r0 = tid/14,  k0 = tid%14;
  const int i1 = tid + 256;
  const int r1 = i1/14,   k1 = i1%14;

  float syn1[2] = {0,0}, m1p[2] = {0,0}, syn2[2] = {0,0}, m2p[2] = {0,0};
  float accf[2] = {0,0};
  const float invn = (1.0f - __expf(-0.05f)) / (1.0f - __expf(-0.05f*512.0f));
  int bar_dead = 0;

  for (int t = 0; t < T_STEPS; ++t) {
    const int wp = t & 1, rp = wp ^ 1;

    // ---- stage x_t (plain cached loads; x read-only) ----
    const float* xt = x + ((size_t)t*256 + (size_t)g*ROWS)*14;
    { _Float16 h, l; split16(xt[r0*14 + k0], h, l);
      xstage[r0*32 + k0] = h; xstage[r0*32 + 16 + k0] = l; }
    if (i1 < 448) {
      _Float16 h, l; split16(xt[r1*14 + k1], h, l);
      xstage[r1*32 + k1] = h; xstage[r1*32 + 16 + k1] = l; }
    __syncthreads();

    // ================= phase A: gates1 partials (wave's kb slice) ==========
    const char* baseH = (const char*)(actb + (size_t)((rp*5 + 0)*8 + g)*ACT_ELEMS);
    const char* baseL = (const char*)(actb + (size_t)((rp*5 + 1)*8 + g)*ACT_ELEMS);
    H8 fh[4][2], fl[4][2];
#pragma unroll
    for (int kl = 0; kl < 4; ++kl) {
      const int kb = wave*4 + kl;
      const size_t o0 = (size_t)(((kb*2 + 0)*64 + lane)*16);
      const size_t o1 = (size_t)(((kb*2 + 1)*64 + lane)*16);
      LDG16(fh[kl][0], baseH + o0);  LDG16(fh[kl][1], baseH + o1);
      LDG16(fl[kl][0], baseL + o0);  LDG16(fl[kl][1], baseL + o1);
    }
    floatx4 acc[4][2];
#pragma unroll
    for (int q = 0; q < 4; ++q) { acc[q][0] = (floatx4){0,0,0,0}; acc[q][1] = (floatx4){0,0,0,0}; }
    {  // x contribution overlaps the load round (wave == gate)
      half8 xa0 = *(const half8*)&xstage[l15*32 + kr];
      half8 xa1 = *(const half8*)&xstage[(16 + l15)*32 + kr];
      acc[wave][0] = MFMA(xa0, wX1, acc[wave][0]);  acc[wave][1] = MFMA(xa1, wX1, acc[wave][1]);
      acc[wave][0] = MFMA(xa0, wX2, acc[wave][0]);  acc[wave][1] = MFMA(xa1, wX2, acc[wave][1]);
    }
    // pipelined waits: kl0/kl1 ready at vmcnt(8), kl2/kl3 at vmcnt(0)
    asm volatile("s_waitcnt vmcnt(8)"
      : "+v"(fh[0][0].i), "+v"(fh[0][1].i), "+v"(fl[0][0].i), "+v"(fl[0][1].i),
        "+v"(fh[1][0].i), "+v"(fh[1][1].i), "+v"(fl[1][0].i), "+v"(fl[1][1].i)
      : : "memory");
#pragma unroll
    for (int kl = 0; kl < 2; ++kl)
#pragma unroll
      for (int q = 0; q < 4; ++q) {
        acc[q][0] = MFMA(fh[kl][0].h, wAh[q][kl], acc[q][0]);
        acc[q][1] = MFMA(fh[kl][1].h, wAh[q][kl], acc[q][1]);
        acc[q][0] = MFMA(fh[kl][0].h, wAl[q][kl], acc[q][0]);
        acc[q][1] = MFMA(fh[kl][1].h, wAl[q][kl], acc[q][1]);
        acc[q][0] = MFMA(fl[kl][0].h, wAh[q][kl], acc[q][0]);
        acc[q][1] = MFMA(fl[kl][1].h, wAh[q][kl], acc[q][1]);
      }
    asm volatile("s_waitcnt vmcnt(0)"
      : "+v"(fh[2][0].i), "+v"(fh[2][1].i), "+v"(fl[2][0].i), "+v"(fl[2][1].i),
        "+v"(fh[3][0].i), "+v"(fh[3][1].i), "+v"(fl[3][0].i), "+v"(fl[3][1].i)
      : : "memory");
#pragma unroll
    for (int kl = 2; kl < 4; ++kl)
#pragma unroll
      for (int q = 0; q < 4; ++q) {
        acc[q][0] = MFMA(fh[kl][0].h, wAh[q][kl], acc[q][0]);
        acc[q][1] = MFMA(fh[kl][1].h, wAh[q][kl], acc[q][1]);
        acc[q][0] = MFMA(fh[kl][0].h, wAl[q][kl], acc[q][0]);
        acc[q][1] = MFMA(fh[kl][1].h, wAl[q][kl], acc[q][1]);
        acc[q][0] = MFMA(fl[kl][0].h, wAh[q][kl], acc[q][0]);
        acc[q][1] = MFMA(fl[kl][1].h, wAh[q][kl], acc[q][1]);
      }
#pragma unroll
    for (int q = 0; q < 4; ++q)
#pragma unroll
      for (int tl = 0; tl < 2; ++tl)
#pragma unroll
        for (int p = 0; p < 4; ++p)
          pbuf[wave][(q*32 + tl*16 + lg*4 + p)*PB_STRIDE + l15] = acc[q][tl][p];
    __syncthreads();

    // ---- ew1: sum 4 wave-partials, gate math, MALL-coherent u32 stores ----
    {
      unsigned* m1hW = (unsigned*)(actb + (size_t)((wp*5 + 0)*8 + g)*ACT_ELEMS);
      unsigned* m1lW = (unsigned*)(actb + (size_t)((wp*5 + 1)*8 + g)*ACT_ELEMS);
      unsigned* spW  = (unsigned*)(actb + (size_t)((wp*5 + 2)*8 + g)*ACT_ELEMS);
      _Float16 mh[2], ml[2], sp[2];
#pragma unroll
      for (int c = 0; c < 2; ++c) {
        float pi = 0, pf = 0, pg = 0, po = 0;
#pragma unroll
        for (int w = 0; w < 4; ++w) {
          pi += pbuf[w][(0*32 + eb)*PB_STRIDE + ehl + c];
          pf += pbuf[w][(1*32 + eb)*PB_STRIDE + ehl + c];
          pg += pbuf[w][(2*32 + eb)*PB_STRIDE + ehl + c];
          po += pbuf[w][(3*32 + eb)*PB_STRIDE + ehl + c];
        }
        float iv = sigm(pi), fv = sigm(pf), gv = tanhf_(pg), ov = sigm(po);
        float cnew = fv*syn1[c] + iv*gv;
        syn1[c] = cnew;
        float hnew = ov*tanhf_(cnew);
        float m1 = hnew - ((m1p[c] > thr1) ? thr1 : 0.0f);   // detached reset
        m1p[c] = m1;
        split16(m1, mh[c], ml[c]);
        sp[c] = ((m1 - thr1) > 0.0f) ? (_Float16)1.0f : (_Float16)0.0f;
      }
      st_u32(m1hW + u32i, pack2(mh[0], mh[1]));
      st_u32(m1lW + u32i, pack2(ml[0], ml[1]));
      st_u32(spW  + u32i, pack2(sp[0], sp[1]));
    }

    // ---- group barrier (agent scope, R5-proven); per-wave store drain ----
    asm volatile("s_waitcnt vmcnt(0)" ::: "memory");
    __syncthreads();
    if (tid == 0 && !bar_dead) {
      __hip_atomic_fetch_add(cntp, 1u, __ATOMIC_RELAXED, __HIP_MEMORY_SCOPE_AGENT);
      unsigned target = 32u*(unsigned)(t + 1);
      int tries = 0;
      while (__hip_atomic_load(cntp, __ATOMIC_RELAXED, __HIP_MEMORY_SCOPE_AGENT) < target) {
        __builtin_amdgcn_s_sleep(1);
        if (++tries > (1 << 20)) { bar_dead = 1; break; }   // anti-hang fuse
      }
    }
    __syncthreads();
    __atomic_signal_fence(__ATOMIC_SEQ_CST);   // compiler-only: no load hoisting

    // ================= phase B: gates2 partials ============================
    const char* baseS  = (const char*)(actb + (size_t)((wp*5 + 2)*8 + g)*ACT_ELEMS);
    const char* base2H = (const char*)(actb + (size_t)((rp*5 + 3)*8 + g)*ACT_ELEMS);
    const char* base2L = (const char*)(actb + (size_t)((rp*5 + 4)*8 + g)*ACT_ELEMS);
#pragma unroll
    for (int q = 0; q < 4; ++q) { acc[q][0] = (floatx4){0,0,0,0}; acc[q][1] = (floatx4){0,0,0,0}; }
#pragma unroll
    for (int hc = 0; hc < 2; ++hc) {     // strict 2-batch: bounded reg pressure
      H8 sb[2][2], mbh[2][2], mbl[2][2];
#pragma unroll
      for (int kc = 0; kc < 2; ++kc) {
        const int kb = wave*4 + hc*2 + kc;
        const size_t o0 = (size_t)(((kb*2 + 0)*64 + lane)*16);
        const size_t o1 = (size_t)(((kb*2 + 1)*64 + lane)*16);
        LDG16(sb[kc][0],  baseS  + o0);  LDG16(sb[kc][1],  baseS  + o1);
        LDG16(mbh[kc][0], base2H + o0);  LDG16(mbh[kc][1], base2H + o1);
        LDG16(mbl[kc][0], base2L + o0);  LDG16(mbl[kc][1], base2L + o1);
      }
      asm volatile("s_waitcnt vmcnt(0)"
        : "+v"(sb[0][0].i), "+v"(sb[0][1].i), "+v"(mbh[0][0].i), "+v"(mbh[0][1].i),
          "+v"(mbl[0][0].i), "+v"(mbl[0][1].i),
          "+v"(sb[1][0].i), "+v"(sb[1][1].i), "+v"(mbh[1][0].i), "+v"(mbh[1][1].i),
          "+v"(mbl[1][0].i), "+v"(mbl[1][1].i)
        : : "memory");
#pragma unroll
      for (int kc = 0; kc < 2; ++kc) {
        const int kl = hc*2 + kc;
#pragma unroll
        for (int q = 0; q < 4; ++q) {
          half8 wIl = *(const half8*)&wIloLds[(((wave*4 + kl)*4 + q)*64 + lane)*8];
          acc[q][0] = MFMA(sb[kc][0].h,  wIh[q][kl], acc[q][0]);
          acc[q][1] = MFMA(sb[kc][1].h,  wIh[q][kl], acc[q][1]);
          acc[q][0] = MFMA(sb[kc][0].h,  wIl,        acc[q][0]);
          acc[q][1] = MFMA(sb[kc][1].h,  wIl,        acc[q][1]);
          acc[q][0] = MFMA(mbh[kc][0].h, wHh[q][kl], acc[q][0]);
          acc[q][1] = MFMA(mbh[kc][1].h, wHh[q][kl], acc[q][1]);
          acc[q][0] = MFMA(mbh[kc][0].h, wHl[q][kl], acc[q][0]);
          acc[q][1] = MFMA(mbh[kc][1].h, wHl[q][kl], acc[q][1]);
          acc[q][0] = MFMA(mbl[kc][0].h, wHh[q][kl], acc[q][0]);
          acc[q][1] = MFMA(mbl[kc][1].h, wHh[q][kl], acc[q][1]);
        }
      }
    }
#pragma unroll
    for (int q = 0; q < 4; ++q)
#pragma unroll
      for (int tl = 0; tl < 2; ++tl)
#pragma unroll
        for (int p = 0; p < 4; ++p)
          pbuf[wave][(q*32 + tl*16 + lg*4 + p)*PB_STRIDE + l15] = acc[q][tl][p];
    __syncthreads();

    // ---- ew2 + temporal-attention accumulation ----
    float wt = __expf(0.05f*(float)(t + 1 - T_STEPS)) * invn;
    {
      unsigned* m2hW = (unsigned*)(actb + (size_t)((wp*5 + 3)*8 + g)*ACT_ELEMS);
      unsigned* m2lW = (unsigned*)(actb + (size_t)((wp*5 + 4)*8 + g)*ACT_ELEMS);
      _Float16 mh[2], ml[2];
#pragma unroll
      for (int c = 0; c < 2; ++c) {
        float pi = b2s[0*16 + ehl + c], pf = b2s[1*16 + ehl + c];
        float pg = b2s[2*16 + ehl + c], po = b2s[3*16 + ehl + c];
#pragma unroll
        for (int w = 0; w < 4; ++w) {
          pi += pbuf[w][(0*32 + eb)*PB_STRIDE + ehl + c];
          pf += pbuf[w][(1*32 + eb)*PB_STRIDE + ehl + c];
          pg += pbuf[w][(2*32 + eb)*PB_STRIDE + ehl + c];
          po += pbuf[w][(3*32 + eb)*PB_STRIDE + ehl + c];
        }
        float iv = sigm(pi), fv = sigm(pf), gv = tanhf_(pg), ov = sigm(po);
        float cnew = fv*syn2[c] + iv*gv;
        syn2[c] = cnew;
        float hnew = ov*tanhf_(cnew);
        float m2 = hnew - ((m2p[c] > thr2) ? thr2 : 0.0f);
        m2p[c] = m2;
        accf[c] += wt * m2;
        split16(m2, mh[c], ml[c]);
      }
      st_u32(m2hW + u32i, pack2(mh[0], mh[1]));
      st_u32(m2lW + u32i, pack2(ml[0], ml[1]));
    }
    // m2 stores drain at next step's barrier (consumed after it)
  }

  // ---- epilogue: final_mem @ Wfc^T + bfc ----
  float part[8];
#pragma unroll
  for (int c = 0; c < 8; ++c)
    part[c] = accf[0]*Wfc[c*HDIM + ehg] + accf[1]*Wfc[c*HDIM + ehg + 1];
#pragma unroll
  for (int off = 1; off < 8; off <<= 1)   // reduce over the 8 h-pair lanes
#pragma unroll
    for (int c = 0; c < 8; ++c)
      part[c] += __shfl_xor(part[c], off, 64);
  {
    int c = tid & 7;
    __hip_atomic_store(&partb[((size_t)(g*32 + cs)*32 + (size_t)eb)*8 + c], part[c],
                       __ATOMIC_RELAXED, __HIP_MEMORY_SCOPE_AGENT);
  }
  asm volatile("s_waitcnt vmcnt(0)" ::: "memory");
  __syncthreads();
  if (tid == 0 && !bar_dead) {
    __hip_atomic_fetch_add(cntp, 1u, __ATOMIC_RELAXED, __HIP_MEMORY_SCOPE_AGENT);
    unsigned target = 32u*513u;
    int tries = 0;
    while (__hip_atomic_load(cntp, __ATOMIC_RELAXED, __HIP_MEMORY_SCOPE_AGENT) < target) {
      __builtin_amdgcn_s_sleep(1);
      if (++tries > (1 << 20)) break;
    }
  }
  __syncthreads();
  __atomic_signal_fence(__ATOMIC_SEQ_CST);

  if (cs == 0) {   // wg 0 of each group reduces its group's 32x8 outputs
    int b = tid >> 3, c = tid & 7;
    float s = bfc[c];
#pragma unroll 4
    for (int jj = 0; jj < 32; ++jj)
      s += __hip_atomic_load(&partb[((size_t)(g*32 + jj)*32 + (size_t)b)*8 + c],
                             __ATOMIC_RELAXED, __HIP_MEMORY_SCOPE_AGENT);
    out[(g*ROWS + b)*8 + c] = s;
  }
}

extern "C" void kernel_launch(void* const* d_in, const int* in_sizes, int n_in,
                              void* d_out, int out_size, void* d_ws, size_t ws_size,
                              hipStream_t stream) {
  (void)in_sizes; (void)n_in;
  const float* x    = (const float*)d_in[0];
  const float* Wih1 = (const float*)d_in[1];
  const float* Whh1 = (const float*)d_in[2];
  const float* bih1 = (const float*)d_in[3];
  const float* bhh1 = (const float*)d_in[4];
  const float* thr1 = (const float*)d_in[5];
  const float* Wih2 = (const float*)d_in[6];
  const float* Whh2 = (const float*)d_in[7];
  const float* bih2 = (const float*)d_in[8];
  const float* bhh2 = (const float*)d_in[9];
  const float* thr2 = (const float*)d_in[10];
  const float* Wfc  = (const float*)d_in[11];
  const float* bfc  = (const float*)d_in[12];
  float* out = (float*)d_out;
  unsigned char* ws = (unsigned char*)d_ws;

  if (ws_size < (size_t)(WS_PART_OFF + WS_PART_BYTES)) {
    hipError_t e1 = hipMemsetAsync(d_out, 0x7f, (size_t)out_size*4, stream);
    (void)e1;
    return;
  }
  // zero barrier counters + both activation parities (t=0 reads zeros = init)
  hipError_t e2 = hipMemsetAsync(d_ws, 0, WS_MEMSET_BYTES, stream);
  (void)e2;

  slstm_kernel<<<dim3(256), dim3(256), 0, stream>>>(
      x, Wih1, Whh1, bih1, bhh1, thr1,
      Wih2, Whh2, bih2, bhh2, thr2, Wfc, bfc, out, ws);
}